// Round 1
// baseline (12679.198 us; speedup 1.0000x reference)
//
#include <hip/hip_runtime.h>
#include <hip/hip_bf16.h>
#include <math.h>

#define B_N 32768
#define COORD 64
#define DG 2048
#define CA 256
#define K_ACT 81
#define SETTLE_STEPS 5
#define GAIN 0.7f
#define LN_EPS 1e-5f
#define COS_EPS 1e-8f
#define BLK_ROWS 8

__device__ __forceinline__ float wave_sum(float v) {
#pragma unroll
  for (int d = 1; d < 64; d <<= 1) v += __shfl_xor(v, d);
  return v;
}

__device__ __forceinline__ float dot4(float4 a, float4 b) {
  return a.x * b.x + a.y * b.y + a.z * b.z + a.w * b.w;
}

__device__ __forceinline__ unsigned int okey(float f) {
  unsigned int u = __float_as_uint(f);
  return (u & 0x80000000u) ? ~u : (u | 0x80000000u);
}

// ---- Kernel 1: column sums of coords (for buf) ----
__global__ void colsum_kernel(const float* __restrict__ coords,
                              float* __restrict__ colsum) {
  int tid = threadIdx.x;
  int col = tid & 63;
  int rg = tid >> 6;  // 0..3
  float s = 0.f;
  int base = blockIdx.x * 128;  // 128 rows per block, 256 blocks
#pragma unroll 4
  for (int i = 0; i < 32; ++i) {
    int r = base + rg + i * 4;
    s += coords[r * COORD + col];
  }
  __shared__ float sh[256];
  sh[tid] = s;
  __syncthreads();
  if (tid < 64) {
    float t = sh[tid] + sh[tid + 64] + sh[tid + 128] + sh[tid + 192];
    atomicAdd(&colsum[tid], t);
  }
}

// ---- Kernel 2: transpose W_mossy (CA, DG) -> WmT (DG, CA) ----
__global__ void transpose_kernel(const float* __restrict__ Wm,
                                 float* __restrict__ WmT) {
  int j = blockIdx.x;   // 0..2047
  int c = threadIdx.x;  // 0..255
  WmT[j * CA + c] = Wm[c * DG + j];
}

// ---- Kernel 3: fused per-row pipeline. 8 waves/block, 1 wave = 1 row ----
__global__ __launch_bounds__(512, 1) void mega_kernel(
    const float* __restrict__ coords,
    const float* __restrict__ ec_gamma, const float* __restrict__ ec_beta,
    const float* __restrict__ W_pp, const float* __restrict__ b_pp,
    const float* __restrict__ dg_gamma, const float* __restrict__ dg_beta,
    const float* __restrict__ W_rec,
    const float* __restrict__ W_sc, const float* __restrict__ b_sc,
    const float* __restrict__ W_ta, const float* __restrict__ b_ta,
    const float* __restrict__ W_cs, const float* __restrict__ W_cd,
    const float* __restrict__ W_og, const float* __restrict__ b_og,
    const float* __restrict__ colsum, const float* __restrict__ WmT,
    float* __restrict__ out) {
  __shared__ __align__(16) float proj[BLK_ROWS][DG];
  __shared__ __align__(16) float ec_s[BLK_ROWS][COORD];
  __shared__ __align__(16) float state_s[BLK_ROWS][CA];
  __shared__ __align__(16) float ca1_s[BLK_ROWS][CA];
  __shared__ __align__(16) float dir_s[BLK_ROWS][CA];
  __shared__ __align__(16) float comb_s[BLK_ROWS][CA];
  __shared__ unsigned int hist[BLK_ROWS][256];
  __shared__ int sel_s[BLK_ROWS][96];

  const int w = threadIdx.x >> 6;
  const int l = threadIdx.x & 63;
  const int row = blockIdx.x * BLK_ROWS + w;

  // ---- EC layernorm (one value per lane) ----
  float x = coords[row * COORD + l] + (0.05f / (float)B_N) * colsum[l];
  float mu = wave_sum(x) * (1.0f / 64.0f);
  float d0 = x - mu;
  float var = wave_sum(d0 * d0) * (1.0f / 64.0f);
  float ec = d0 * rsqrtf(var + LN_EPS) * ec_gamma[l] + ec_beta[l];
  ec_s[w][l] = ec;
  __syncthreads();

  // ---- proj = relu(ec @ W_pp^T + b_pp), then LN over 2048 ----
  float sum = 0.f, sumsq = 0.f;
  for (int i = 0; i < 32; ++i) {
    int j = i * 64 + l;
    const float* wp = W_pp + j * COORD;
    float acc = b_pp[j];
#pragma unroll
    for (int k = 0; k < COORD; k += 4) {
      float4 e4 = *reinterpret_cast<const float4*>(&ec_s[w][k]);
      float4 w4 = *reinterpret_cast<const float4*>(wp + k);
      acc += dot4(e4, w4);
    }
    float h = fmaxf(acc, 0.f);
    proj[w][j] = h;
    sum += h;
    sumsq += h * h;
  }
  sum = wave_sum(sum);
  sumsq = wave_sum(sumsq);
  float mu2 = sum * (1.0f / (float)DG);
  float var2 = sumsq * (1.0f / (float)DG) - mu2 * mu2;
  float rs2 = rsqrtf(var2 + LN_EPS);
  for (int i = 0; i < 32; ++i) {
    int j = i * 64 + l;
    float v = (proj[w][j] - mu2) * rs2 * dg_gamma[j] + dg_beta[j];
    proj[w][j] = v;
  }
  __syncthreads();

  // ---- radix-select: exact key of 81st-largest ----
  unsigned int prefix = 0;
  unsigned int rem = K_ACT;
#pragma unroll 1
  for (int pass = 0; pass < 4; ++pass) {
    int sh = 24 - 8 * pass;
#pragma unroll
    for (int b = l; b < 256; b += 64) hist[w][b] = 0;
    __syncthreads();
    for (int i = 0; i < 32; ++i) {
      int j = i * 64 + l;
      unsigned int key = okey(proj[w][j]);
      bool ok = (pass == 0) || ((key >> (sh + 8)) == prefix);
      if (ok) atomicAdd(&hist[w][(key >> sh) & 255u], 1u);
    }
    __syncthreads();
    unsigned int h0 = hist[w][4 * l + 0], h1 = hist[w][4 * l + 1];
    unsigned int h2 = hist[w][4 * l + 2], h3 = hist[w][4 * l + 3];
    unsigned int own = h0 + h1 + h2 + h3;
    unsigned int inc = own;
#pragma unroll
    for (int d = 1; d < 64; d <<= 1) {
      unsigned int v = __shfl_down(inc, d);
      if (l + d < 64) inc += v;
    }
    unsigned int cnt = inc - own;  // total in lanes above (higher digits)
    unsigned int pk = 0;
    {
      unsigned int hb;
      hb = h3; if (cnt < rem && rem <= cnt + hb) pk = ((rem - cnt) << 8) | (unsigned)(4 * l + 3); cnt += hb;
      hb = h2; if (cnt < rem && rem <= cnt + hb) pk = ((rem - cnt) << 8) | (unsigned)(4 * l + 2); cnt += hb;
      hb = h1; if (cnt < rem && rem <= cnt + hb) pk = ((rem - cnt) << 8) | (unsigned)(4 * l + 1); cnt += hb;
      hb = h0; if (cnt < rem && rem <= cnt + hb) pk = ((rem - cnt) << 8) | (unsigned)(4 * l + 0); cnt += hb;
    }
#pragma unroll
    for (int d = 1; d < 64; d <<= 1) pk |= __shfl_xor(pk, d);
    prefix = (prefix << 8) | (pk & 255u);
    rem = pk >> 8;
    __syncthreads();
  }
  const unsigned int Tkey = prefix;
  const unsigned int rem_final = rem;

  // ---- select + compact indices (index order == jax tie-break) ----
  const unsigned long long below = (1ull << l) - 1ull;
  int basec = 0;
  unsigned int eq_seen = 0;
  for (int i = 0; i < 32; ++i) {
    int j = i * 64 + l;
    unsigned int key = okey(proj[w][j]);
    bool gt = key > Tkey;
    bool eq = (key == Tkey);
    unsigned long long em = __ballot(eq);
    unsigned int eq_before = eq_seen + (unsigned)__popcll(em & below);
    bool sel = gt || (eq && (eq_before < rem_final));
    unsigned long long sm = __ballot(sel);
    int pos = basec + (int)__popcll(sm & below);
    if (sel) sel_s[w][pos] = j;
    basec += (int)__popcll(sm);
    eq_seen += (unsigned)__popcll(em);
  }
  __syncthreads();

  // ---- cue = dg @ W_mossy^T (sparse, coalesced via WmT) ----
  float c0 = 0, c1 = 0, c2 = 0, c3 = 0;
  for (int k = 0; k < K_ACT; ++k) {
    int j = sel_s[w][k];
    float v = proj[w][j];
    float4 wv = *reinterpret_cast<const float4*>(WmT + (size_t)j * CA + 4 * l);
    c0 += v * wv.x;
    c1 += v * wv.y;
    c2 += v * wv.z;
    c3 += v * wv.w;
  }
  {
    float4 st;
    st.x = c0; st.y = c1; st.z = c2; st.w = c3;
    *reinterpret_cast<float4*>(&state_s[w][4 * l]) = st;
  }
  __syncthreads();

  // ---- settle: 5x state = tanh(0.7*W_rec@state + 0.3*cue) ----
  const float* wr0 = W_rec + (size_t)(4 * l + 0) * CA;
  const float* wr1 = W_rec + (size_t)(4 * l + 1) * CA;
  const float* wr2 = W_rec + (size_t)(4 * l + 2) * CA;
  const float* wr3 = W_rec + (size_t)(4 * l + 3) * CA;
  for (int it = 0; it < SETTLE_STEPS; ++it) {
    float a0 = 0, a1 = 0, a2 = 0, a3 = 0;
    for (int j = 0; j < CA; j += 4) {
      float4 s4 = *reinterpret_cast<const float4*>(&state_s[w][j]);
      a0 += dot4(s4, *reinterpret_cast<const float4*>(wr0 + j));
      a1 += dot4(s4, *reinterpret_cast<const float4*>(wr1 + j));
      a2 += dot4(s4, *reinterpret_cast<const float4*>(wr2 + j));
      a3 += dot4(s4, *reinterpret_cast<const float4*>(wr3 + j));
    }
    float4 ns;
    ns.x = tanhf(GAIN * a0 + (1.f - GAIN) * c0);
    ns.y = tanhf(GAIN * a1 + (1.f - GAIN) * c1);
    ns.z = tanhf(GAIN * a2 + (1.f - GAIN) * c2);
    ns.w = tanhf(GAIN * a3 + (1.f - GAIN) * c3);
    *reinterpret_cast<float4*>(&state_s[w][4 * l]) = ns;
    __syncthreads();
  }

  // ---- ca1_input = state @ W_sc^T + b_sc ----
  float ci0, ci1, ci2, ci3;
  {
    const float* q0 = W_sc + (size_t)(4 * l + 0) * CA;
    const float* q1 = W_sc + (size_t)(4 * l + 1) * CA;
    const float* q2 = W_sc + (size_t)(4 * l + 2) * CA;
    const float* q3 = W_sc + (size_t)(4 * l + 3) * CA;
    float a0 = 0, a1 = 0, a2 = 0, a3 = 0;
    for (int j = 0; j < CA; j += 4) {
      float4 s4 = *reinterpret_cast<const float4*>(&state_s[w][j]);
      a0 += dot4(s4, *reinterpret_cast<const float4*>(q0 + j));
      a1 += dot4(s4, *reinterpret_cast<const float4*>(q1 + j));
      a2 += dot4(s4, *reinterpret_cast<const float4*>(q2 + j));
      a3 += dot4(s4, *reinterpret_cast<const float4*>(q3 + j));
    }
    ci0 = a0 + b_sc[4 * l + 0];
    ci1 = a1 + b_sc[4 * l + 1];
    ci2 = a2 + b_sc[4 * l + 2];
    ci3 = a3 + b_sc[4 * l + 3];
    float4 t;
    t.x = ci0; t.y = ci1; t.z = ci2; t.w = ci3;
    *reinterpret_cast<float4*>(&ca1_s[w][4 * l]) = t;
  }

  // ---- direct = ec @ W_ta^T + b_ta ----
  float dr0, dr1, dr2, dr3;
  {
    const float* t0 = W_ta + (size_t)(4 * l + 0) * COORD;
    const float* t1 = W_ta + (size_t)(4 * l + 1) * COORD;
    const float* t2 = W_ta + (size_t)(4 * l + 2) * COORD;
    const float* t3 = W_ta + (size_t)(4 * l + 3) * COORD;
    float a0 = b_ta[4 * l + 0], a1 = b_ta[4 * l + 1];
    float a2 = b_ta[4 * l + 2], a3 = b_ta[4 * l + 3];
#pragma unroll
    for (int k = 0; k < COORD; k += 4) {
      float4 e4 = *reinterpret_cast<const float4*>(&ec_s[w][k]);
      a0 += dot4(e4, *reinterpret_cast<const float4*>(t0 + k));
      a1 += dot4(e4, *reinterpret_cast<const float4*>(t1 + k));
      a2 += dot4(e4, *reinterpret_cast<const float4*>(t2 + k));
      a3 += dot4(e4, *reinterpret_cast<const float4*>(t3 + k));
    }
    dr0 = a0; dr1 = a1; dr2 = a2; dr3 = a3;
    float4 t;
    t.x = dr0; t.y = dr1; t.z = dr2; t.w = dr3;
    *reinterpret_cast<float4*>(&dir_s[w][4 * l]) = t;
  }
  __syncthreads();

  // ---- s_proj = ca1 @ W_cs^T ; d_proj = direct @ W_cd^T ----
  float sp0 = 0, sp1 = 0, sp2 = 0, sp3 = 0;
  float dp0 = 0, dp1 = 0, dp2 = 0, dp3 = 0;
  {
    const float* q0 = W_cs + (size_t)(4 * l + 0) * CA;
    const float* q1 = W_cs + (size_t)(4 * l + 1) * CA;
    const float* q2 = W_cs + (size_t)(4 * l + 2) * CA;
    const float* q3 = W_cs + (size_t)(4 * l + 3) * CA;
    const float* r0 = W_cd + (size_t)(4 * l + 0) * CA;
    const float* r1 = W_cd + (size_t)(4 * l + 1) * CA;
    const float* r2 = W_cd + (size_t)(4 * l + 2) * CA;
    const float* r3 = W_cd + (size_t)(4 * l + 3) * CA;
    for (int j = 0; j < CA; j += 4) {
      float4 a4 = *reinterpret_cast<const float4*>(&ca1_s[w][j]);
      float4 d4 = *reinterpret_cast<const float4*>(&dir_s[w][j]);
      sp0 += dot4(a4, *reinterpret_cast<const float4*>(q0 + j));
      sp1 += dot4(a4, *reinterpret_cast<const float4*>(q1 + j));
      sp2 += dot4(a4, *reinterpret_cast<const float4*>(q2 + j));
      sp3 += dot4(a4, *reinterpret_cast<const float4*>(q3 + j));
      dp0 += dot4(d4, *reinterpret_cast<const float4*>(r0 + j));
      dp1 += dot4(d4, *reinterpret_cast<const float4*>(r1 + j));
      dp2 += dot4(d4, *reinterpret_cast<const float4*>(r2 + j));
      dp3 += dot4(d4, *reinterpret_cast<const float4*>(r3 + j));
    }
  }

  // ---- cosine novelty gate ----
  float sdot = sp0 * dp0 + sp1 * dp1 + sp2 * dp2 + sp3 * dp3;
  float snrm = sp0 * sp0 + sp1 * sp1 + sp2 * sp2 + sp3 * sp3;
  float dnrm = dp0 * dp0 + dp1 * dp1 + dp2 * dp2 + dp3 * dp3;
  sdot = wave_sum(sdot);
  snrm = wave_sum(snrm);
  dnrm = wave_sum(dnrm);
  float sn = fmaxf(sqrtf(snrm), COS_EPS);
  float dn = fmaxf(sqrtf(dnrm), COS_EPS);
  float cosv = sdot / (sn * dn);
  float nov = fminf(fmaxf(1.f - cosv, 0.f), 1.f);

  // ---- combined + output projection ----
  {
    float4 cb;
    cb.x = nov * dr0 + (1.f - nov) * ci0;
    cb.y = nov * dr1 + (1.f - nov) * ci1;
    cb.z = nov * dr2 + (1.f - nov) * ci2;
    cb.w = nov * dr3 + (1.f - nov) * ci3;
    *reinterpret_cast<float4*>(&comb_s[w][4 * l]) = cb;
  }
  {
    const float* q0 = W_og + (size_t)(4 * l + 0) * CA;
    const float* q1 = W_og + (size_t)(4 * l + 1) * CA;
    const float* q2 = W_og + (size_t)(4 * l + 2) * CA;
    const float* q3 = W_og + (size_t)(4 * l + 3) * CA;
    float a0 = 0, a1 = 0, a2 = 0, a3 = 0;
    for (int j = 0; j < CA; j += 4) {
      float4 s4 = *reinterpret_cast<const float4*>(&comb_s[w][j]);
      a0 += dot4(s4, *reinterpret_cast<const float4*>(q0 + j));
      a1 += dot4(s4, *reinterpret_cast<const float4*>(q1 + j));
      a2 += dot4(s4, *reinterpret_cast<const float4*>(q2 + j));
      a3 += dot4(s4, *reinterpret_cast<const float4*>(q3 + j));
    }
    float4 o;
    o.x = tanhf(a0 + b_og[4 * l + 0]);
    o.y = tanhf(a1 + b_og[4 * l + 1]);
    o.z = tanhf(a2 + b_og[4 * l + 2]);
    o.w = tanhf(a3 + b_og[4 * l + 3]);
    *reinterpret_cast<float4*>(&out[(size_t)row * CA + 4 * l]) = o;
  }
  if (l == 0) out[(size_t)B_N * CA + row] = nov;
}

extern "C" void kernel_launch(void* const* d_in, const int* in_sizes, int n_in,
                              void* d_out, int out_size, void* d_ws,
                              size_t ws_size, hipStream_t stream) {
  const float* coords = (const float*)d_in[0];
  const float* ec_gamma = (const float*)d_in[1];
  const float* ec_beta = (const float*)d_in[2];
  const float* W_pp = (const float*)d_in[3];
  const float* b_pp = (const float*)d_in[4];
  const float* dg_gamma = (const float*)d_in[5];
  const float* dg_beta = (const float*)d_in[6];
  const float* W_mossy = (const float*)d_in[7];
  const float* W_rec = (const float*)d_in[8];
  const float* W_sc = (const float*)d_in[9];
  const float* b_sc = (const float*)d_in[10];
  const float* W_ta = (const float*)d_in[11];
  const float* b_ta = (const float*)d_in[12];
  const float* W_cs = (const float*)d_in[13];
  const float* W_cd = (const float*)d_in[14];
  const float* W_og = (const float*)d_in[15];
  const float* b_og = (const float*)d_in[16];
  float* out = (float*)d_out;

  float* ws = (float*)d_ws;
  float* colsum = ws;           // 64 floats
  float* WmT = ws + 64;         // 2048*256 floats

  hipMemsetAsync(colsum, 0, COORD * sizeof(float), stream);
  colsum_kernel<<<256, 256, 0, stream>>>(coords, colsum);
  transpose_kernel<<<DG, CA, 0, stream>>>(W_mossy, WmT);
  mega_kernel<<<B_N / BLK_ROWS, 512, 0, stream>>>(
      coords, ec_gamma, ec_beta, W_pp, b_pp, dg_gamma, dg_beta, W_rec, W_sc,
      b_sc, W_ta, b_ta, W_cs, W_cd, W_og, b_og, colsum, WmT, out);
}

// Round 3
// 1058.801 us; speedup vs baseline: 11.9751x; 11.9751x over previous
//
#include <hip/hip_runtime.h>
#include <hip/hip_bf16.h>
#include <math.h>

#define B_N 32768
#define COORD 64
#define DG 2048
#define CA 256
#define K_ACT 81
#define SETTLE_STEPS 5
#define GAIN 0.7f
#define LN_EPS 1e-5f
#define COS_EPS 1e-8f

__device__ __forceinline__ float wave_sum(float v) {
#pragma unroll
  for (int d = 1; d < 64; d <<= 1) v += __shfl_xor(v, d);
  return v;
}

__device__ __forceinline__ float dot4(float4 a, float4 b) {
  return a.x * b.x + a.y * b.y + a.z * b.z + a.w * b.w;
}

__device__ __forceinline__ void fma4(float4& a, float s, float4 w) {
  a.x += s * w.x; a.y += s * w.y; a.z += s * w.z; a.w += s * w.w;
}

__device__ __forceinline__ unsigned int okey(float f) {
  unsigned int u = __float_as_uint(f);
  return (u & 0x80000000u) ? ~u : (u | 0x80000000u);
}

// ---- column sums of coords (for buf) ----
__global__ void colsum_kernel(const float* __restrict__ coords,
                              float* __restrict__ colsum) {
  int tid = threadIdx.x;
  int col = tid & 63;
  int rg = tid >> 6;
  float s = 0.f;
  int base = blockIdx.x * 128;
#pragma unroll 4
  for (int i = 0; i < 32; ++i) {
    int r = base + rg + i * 4;
    s += coords[r * COORD + col];
  }
  __shared__ float sh[256];
  sh[tid] = s;
  __syncthreads();
  if (tid < 64) {
    float t = sh[tid] + sh[tid + 64] + sh[tid + 128] + sh[tid + 192];
    atomicAdd(&colsum[tid], t);
  }
}

// ---- generic transpose: T[c*R + r] = S[r*C + c] ----
__global__ void transpose_any(const float* __restrict__ S,
                              float* __restrict__ T, int R, int C) {
  int idx = blockIdx.x * 256 + threadIdx.x;
  if (idx < R * C) {
    int r = idx / C, c = idx - r * C;
    T[c * R + r] = S[r * C + c];
  }
}

// ============ mega1: EC-LN -> proj(+LN) -> radix top-81 -> cue ============
// 512 thr = 8 waves; 8 rows/block. Phase B: wave w owns j-chunk [256w,256w+256)
// for ALL 8 rows (W_ppT read once per block). Phase C: wave w owns row w.
__global__ __launch_bounds__(512, 4) void mega1(
    const float* __restrict__ coords, const float* __restrict__ colsum,
    const float* __restrict__ ec_gamma, const float* __restrict__ ec_beta,
    const float* __restrict__ W_ppT, const float* __restrict__ b_pp,
    const float* __restrict__ dg_gamma, const float* __restrict__ dg_beta,
    const float* __restrict__ WmT, float* __restrict__ cue_g) {
  __shared__ __align__(16) float proj_s[8][DG];
  __shared__ __align__(16) float ec_s[8][COORD];
  __shared__ unsigned int hist[8][256];
  __shared__ float psum_s[8][8], psq_s[8][8];
  __shared__ int sel_s[8][88];

  const int w = threadIdx.x >> 6;
  const int l = threadIdx.x & 63;
  const int row0 = blockIdx.x * 8;

  // ---- A: EC layernorm (wave w -> row w) ----
  {
    int row = row0 + w;
    float x = coords[row * COORD + l] + (0.05f / (float)B_N) * colsum[l];
    float mu = wave_sum(x) * (1.f / 64.f);
    float d = x - mu;
    float var = wave_sum(d * d) * (1.f / 64.f);
    ec_s[w][l] = d * rsqrtf(var + LN_EPS) * ec_gamma[l] + ec_beta[l];
  }
  __syncthreads();

  // ---- B: proj chunk for all 8 rows ----
  {
    float4 acc[8];
#pragma unroll
    for (int r = 0; r < 8; ++r) acc[r] = make_float4(0.f, 0.f, 0.f, 0.f);
    const float4* wp4 = reinterpret_cast<const float4*>(W_ppT);
    const int cbase = 64 * w + l;  // float4 index within full 2048-row
    for (int kg = 0; kg < 16; ++kg) {
      float4 w40 = wp4[(4 * kg + 0) * 512 + cbase];
      float4 w41 = wp4[(4 * kg + 1) * 512 + cbase];
      float4 w42 = wp4[(4 * kg + 2) * 512 + cbase];
      float4 w43 = wp4[(4 * kg + 3) * 512 + cbase];
#pragma unroll
      for (int r = 0; r < 8; ++r) {
        float4 e4 = reinterpret_cast<const float4*>(ec_s[r])[kg];
        fma4(acc[r], e4.x, w40);
        fma4(acc[r], e4.y, w41);
        fma4(acc[r], e4.z, w42);
        fma4(acc[r], e4.w, w43);
      }
    }
    float4 bp = reinterpret_cast<const float4*>(b_pp)[cbase];
#pragma unroll
    for (int r = 0; r < 8; ++r) {
      float4 h;
      h.x = fmaxf(acc[r].x + bp.x, 0.f);
      h.y = fmaxf(acc[r].y + bp.y, 0.f);
      h.z = fmaxf(acc[r].z + bp.z, 0.f);
      h.w = fmaxf(acc[r].w + bp.w, 0.f);
      reinterpret_cast<float4*>(proj_s[r])[cbase] = h;
      float ps = wave_sum(h.x + h.y + h.z + h.w);
      float pq = wave_sum(dot4(h, h));
      if (l == 0) { psum_s[w][r] = ps; psq_s[w][r] = pq; }
    }
  }
  __syncthreads();

  // ---- C: wave w -> row w: LN + radix top-81 + cue ----
  float mu2, rs2;
  {
    float s = 0.f, q = 0.f;
#pragma unroll
    for (int w2 = 0; w2 < 8; ++w2) { s += psum_s[w2][w]; q += psq_s[w2][w]; }
    mu2 = s * (1.f / (float)DG);
    float var = q * (1.f / (float)DG) - mu2 * mu2;
    rs2 = rsqrtf(var + LN_EPS);
  }
  unsigned int key[32];
#pragma unroll 4
  for (int i = 0; i < 32; ++i) {
    int j = i * 64 + l;
    float v = (proj_s[w][j] - mu2) * rs2 * dg_gamma[j] + dg_beta[j];
    proj_s[w][j] = v;
    key[i] = okey(v);
  }

  // radix-select exact key of 81st largest (hist/sel wave-private, no barriers)
  unsigned int prefix = 0, rem = K_ACT;
#pragma unroll 1
  for (int pass = 0; pass < 4; ++pass) {
    int sh = 24 - 8 * pass;
#pragma unroll
    for (int b = l; b < 256; b += 64) hist[w][b] = 0;
#pragma unroll 4
    for (int i = 0; i < 32; ++i) {
      unsigned int k = key[i];
      bool ok = (pass == 0) || ((k >> (sh + 8)) == prefix);
      if (ok) atomicAdd(&hist[w][(k >> sh) & 255u], 1u);
    }
    unsigned int h0 = hist[w][4 * l + 0], h1 = hist[w][4 * l + 1];
    unsigned int h2 = hist[w][4 * l + 2], h3 = hist[w][4 * l + 3];
    unsigned int own = h0 + h1 + h2 + h3;
    unsigned int inc = own;
#pragma unroll
    for (int d = 1; d < 64; d <<= 1) {
      unsigned int v = __shfl_down(inc, d);
      if (l + d < 64) inc += v;
    }
    unsigned int cnt = inc - own;
    unsigned int pk = 0;
    {
      unsigned int hb;
      hb = h3; if (cnt < rem && rem <= cnt + hb) pk = ((rem - cnt) << 8) | (unsigned)(4 * l + 3); cnt += hb;
      hb = h2; if (cnt < rem && rem <= cnt + hb) pk = ((rem - cnt) << 8) | (unsigned)(4 * l + 2); cnt += hb;
      hb = h1; if (cnt < rem && rem <= cnt + hb) pk = ((rem - cnt) << 8) | (unsigned)(4 * l + 1); cnt += hb;
      hb = h0; if (cnt < rem && rem <= cnt + hb) pk = ((rem - cnt) << 8) | (unsigned)(4 * l + 0); cnt += hb;
    }
#pragma unroll
    for (int d = 1; d < 64; d <<= 1) pk |= __shfl_xor(pk, d);
    prefix = (prefix << 8) | (pk & 255u);
    rem = pk >> 8;
  }
  const unsigned int Tkey = prefix;
  const unsigned int rem_final = rem;

  // select + compact (index order == jax tie-break)
  const unsigned long long below = (1ull << l) - 1ull;
  int basec = 0;
  unsigned int eq_seen = 0;
  for (int i = 0; i < 32; ++i) {
    int j = i * 64 + l;
    unsigned int k = key[i];
    bool gt = k > Tkey;
    bool eq = (k == Tkey);
    unsigned long long em = __ballot(eq);
    unsigned int eq_before = eq_seen + (unsigned)__popcll(em & below);
    bool sel = gt || (eq && (eq_before < rem_final));
    unsigned long long sm = __ballot(sel);
    int pos = basec + (int)__popcll(sm & below);
    if (sel) sel_s[w][pos] = j;
    basec += (int)__popcll(sm);
    eq_seen += (unsigned)__popcll(em);
  }

  // cue = sum over selected j of proj[j] * WmT[j][:]
  float4 c4 = make_float4(0.f, 0.f, 0.f, 0.f);
  const float4* wm4 = reinterpret_cast<const float4*>(WmT);
  for (int k = 0; k < K_ACT; ++k) {
    int j = sel_s[w][k];
    float v = proj_s[w][j];
    fma4(c4, v, wm4[j * 64 + l]);
  }
  reinterpret_cast<float4*>(cue_g)[(size_t)(row0 + w) * 64 + l] = c4;
}

// ============ mega2: settle + epilogue. 256 thr = 4 waves, 8 rows/wave =====
// Each wave is an independent 8-row engine: weight float4 loaded once feeds
// 32 FMAs; activations broadcast from wave-private LDS rows. No barriers.
__global__ __launch_bounds__(256, 2) void mega2(
    const float* __restrict__ coords, const float* __restrict__ colsum,
    const float* __restrict__ ec_gamma, const float* __restrict__ ec_beta,
    const float* __restrict__ cue_g,
    const float* __restrict__ W_recT,
    const float* __restrict__ W_scT, const float* __restrict__ b_sc,
    const float* __restrict__ W_taT, const float* __restrict__ b_ta,
    const float* __restrict__ W_csT, const float* __restrict__ W_cdT,
    const float* __restrict__ W_ogT, const float* __restrict__ b_og,
    float* __restrict__ out) {
  __shared__ __align__(16) float bufA[32][CA];  // state -> dir -> combined
  __shared__ __align__(16) float bufB[32][CA];  // ca1
  __shared__ __align__(16) float ec_s[32][COORD];

  const int w = threadIdx.x >> 6;
  const int l = threadIdx.x & 63;
  const int row0 = blockIdx.x * 32 + w * 8;

  // ---- EC layernorm for this wave's 8 rows ----
#pragma unroll 1
  for (int r = 0; r < 8; ++r) {
    int row = row0 + r;
    float x = coords[row * COORD + l] + (0.05f / (float)B_N) * colsum[l];
    float mu = wave_sum(x) * (1.f / 64.f);
    float d = x - mu;
    float var = wave_sum(d * d) * (1.f / 64.f);
    ec_s[w * 8 + r][l] = d * rsqrtf(var + LN_EPS) * ec_gamma[l] + ec_beta[l];
  }

  // ---- load cue, init state ----
  float4 cu[8];
#pragma unroll
  for (int r = 0; r < 8; ++r) {
    cu[r] = reinterpret_cast<const float4*>(cue_g)[(size_t)(row0 + r) * 64 + l];
    reinterpret_cast<float4*>(bufA[w * 8 + r])[l] = cu[r];
  }

  const float4* wr4 = reinterpret_cast<const float4*>(W_recT);
  float4 acc[8];

  // ---- settle x5: state = tanh(0.7*(state @ W_rec^T) + 0.3*cue) ----
#pragma unroll 1
  for (int it = 0; it < SETTLE_STEPS; ++it) {
#pragma unroll
    for (int r = 0; r < 8; ++r) acc[r] = make_float4(0.f, 0.f, 0.f, 0.f);
#pragma unroll 2
    for (int jg = 0; jg < 64; ++jg) {
      float4 w40 = wr4[(4 * jg + 0) * 64 + l];
      float4 w41 = wr4[(4 * jg + 1) * 64 + l];
      float4 w42 = wr4[(4 * jg + 2) * 64 + l];
      float4 w43 = wr4[(4 * jg + 3) * 64 + l];
#pragma unroll
      for (int r = 0; r < 8; ++r) {
        float4 s4 = reinterpret_cast<const float4*>(bufA[w * 8 + r])[jg];
        fma4(acc[r], s4.x, w40);
        fma4(acc[r], s4.y, w41);
        fma4(acc[r], s4.z, w42);
        fma4(acc[r], s4.w, w43);
      }
    }
#pragma unroll
    for (int r = 0; r < 8; ++r) {
      float4 ns;
      ns.x = tanhf(GAIN * acc[r].x + (1.f - GAIN) * cu[r].x);
      ns.y = tanhf(GAIN * acc[r].y + (1.f - GAIN) * cu[r].y);
      ns.z = tanhf(GAIN * acc[r].z + (1.f - GAIN) * cu[r].z);
      ns.w = tanhf(GAIN * acc[r].w + (1.f - GAIN) * cu[r].w);
      reinterpret_cast<float4*>(bufA[w * 8 + r])[l] = ns;
    }
  }

  // ---- ca1 = state @ W_sc^T + b_sc  (ci reuses cu regs) ----
  {
    const float4* ws4 = reinterpret_cast<const float4*>(W_scT);
#pragma unroll
    for (int r = 0; r < 8; ++r) acc[r] = make_float4(0.f, 0.f, 0.f, 0.f);
#pragma unroll 2
    for (int jg = 0; jg < 64; ++jg) {
      float4 w40 = ws4[(4 * jg + 0) * 64 + l];
      float4 w41 = ws4[(4 * jg + 1) * 64 + l];
      float4 w42 = ws4[(4 * jg + 2) * 64 + l];
      float4 w43 = ws4[(4 * jg + 3) * 64 + l];
#pragma unroll
      for (int r = 0; r < 8; ++r) {
        float4 s4 = reinterpret_cast<const float4*>(bufA[w * 8 + r])[jg];
        fma4(acc[r], s4.x, w40);
        fma4(acc[r], s4.y, w41);
        fma4(acc[r], s4.z, w42);
        fma4(acc[r], s4.w, w43);
      }
    }
    float4 bs = reinterpret_cast<const float4*>(b_sc)[l];
#pragma unroll
    for (int r = 0; r < 8; ++r) {
      cu[r].x = acc[r].x + bs.x;
      cu[r].y = acc[r].y + bs.y;
      cu[r].z = acc[r].z + bs.z;
      cu[r].w = acc[r].w + bs.w;
      reinterpret_cast<float4*>(bufB[w * 8 + r])[l] = cu[r];  // ca1
    }
  }

  // ---- direct = ec @ W_ta^T + b_ta ----
  float4 dr[8];
  {
    const float4* wt4 = reinterpret_cast<const float4*>(W_taT);
#pragma unroll
    for (int r = 0; r < 8; ++r) acc[r] = make_float4(0.f, 0.f, 0.f, 0.f);
#pragma unroll 2
    for (int kg = 0; kg < 16; ++kg) {
      float4 w40 = wt4[(4 * kg + 0) * 64 + l];
      float4 w41 = wt4[(4 * kg + 1) * 64 + l];
      float4 w42 = wt4[(4 * kg + 2) * 64 + l];
      float4 w43 = wt4[(4 * kg + 3) * 64 + l];
#pragma unroll
      for (int r = 0; r < 8; ++r) {
        float4 e4 = reinterpret_cast<const float4*>(ec_s[w * 8 + r])[kg];
        fma4(acc[r], e4.x, w40);
        fma4(acc[r], e4.y, w41);
        fma4(acc[r], e4.z, w42);
        fma4(acc[r], e4.w, w43);
      }
    }
    float4 bt = reinterpret_cast<const float4*>(b_ta)[l];
#pragma unroll
    for (int r = 0; r < 8; ++r) {
      dr[r].x = acc[r].x + bt.x;
      dr[r].y = acc[r].y + bt.y;
      dr[r].z = acc[r].z + bt.z;
      dr[r].w = acc[r].w + bt.w;
      reinterpret_cast<float4*>(bufA[w * 8 + r])[l] = dr[r];  // dir (state dead)
    }
  }

  // ---- d_proj = dir @ W_cd^T ----
  float4 dpr[8];
  {
    const float4* wc4 = reinterpret_cast<const float4*>(W_cdT);
#pragma unroll
    for (int r = 0; r < 8; ++r) acc[r] = make_float4(0.f, 0.f, 0.f, 0.f);
#pragma unroll 2
    for (int jg = 0; jg < 64; ++jg) {
      float4 w40 = wc4[(4 * jg + 0) * 64 + l];
      float4 w41 = wc4[(4 * jg + 1) * 64 + l];
      float4 w42 = wc4[(4 * jg + 2) * 64 + l];
      float4 w43 = wc4[(4 * jg + 3) * 64 + l];
#pragma unroll
      for (int r = 0; r < 8; ++r) {
        float4 s4 = reinterpret_cast<const float4*>(bufA[w * 8 + r])[jg];
        fma4(acc[r], s4.x, w40);
        fma4(acc[r], s4.y, w41);
        fma4(acc[r], s4.z, w42);
        fma4(acc[r], s4.w, w43);
      }
    }
#pragma unroll
    for (int r = 0; r < 8; ++r) dpr[r] = acc[r];
  }

  // ---- s_proj = ca1 @ W_cs^T ----
  {
    const float4* wc4 = reinterpret_cast<const float4*>(W_csT);
#pragma unroll
    for (int r = 0; r < 8; ++r) acc[r] = make_float4(0.f, 0.f, 0.f, 0.f);
#pragma unroll 2
    for (int jg = 0; jg < 64; ++jg) {
      float4 w40 = wc4[(4 * jg + 0) * 64 + l];
      float4 w41 = wc4[(4 * jg + 1) * 64 + l];
      float4 w42 = wc4[(4 * jg + 2) * 64 + l];
      float4 w43 = wc4[(4 * jg + 3) * 64 + l];
#pragma unroll
      for (int r = 0; r < 8; ++r) {
        float4 s4 = reinterpret_cast<const float4*>(bufB[w * 8 + r])[jg];
        fma4(acc[r], s4.x, w40);
        fma4(acc[r], s4.y, w41);
        fma4(acc[r], s4.z, w42);
        fma4(acc[r], s4.w, w43);
      }
    }
  }

  // ---- novelty + combined + out ----
#pragma unroll 1
  for (int r = 0; r < 8; ++r) {
    float sd = wave_sum(dot4(acc[r], dpr[r]));
    float sn = wave_sum(dot4(acc[r], acc[r]));
    float dn = wave_sum(dot4(dpr[r], dpr[r]));
    float s_n = fmaxf(sqrtf(sn), COS_EPS);
    float d_n = fmaxf(sqrtf(dn), COS_EPS);
    float nov = fminf(fmaxf(1.f - sd / (s_n * d_n), 0.f), 1.f);
    float4 cb;
    cb.x = nov * dr[r].x + (1.f - nov) * cu[r].x;
    cb.y = nov * dr[r].y + (1.f - nov) * cu[r].y;
    cb.z = nov * dr[r].z + (1.f - nov) * cu[r].z;
    cb.w = nov * dr[r].w + (1.f - nov) * cu[r].w;
    reinterpret_cast<float4*>(bufA[w * 8 + r])[l] = cb;  // combined (dir dead)
    if (l == 0) out[(size_t)B_N * CA + (row0 + r)] = nov;
  }

  // ---- out = tanh(combined @ W_og^T + b_og) ----
  {
    const float4* wo4 = reinterpret_cast<const float4*>(W_ogT);
#pragma unroll
    for (int r = 0; r < 8; ++r) acc[r] = make_float4(0.f, 0.f, 0.f, 0.f);
#pragma unroll 2
    for (int jg = 0; jg < 64; ++jg) {
      float4 w40 = wo4[(4 * jg + 0) * 64 + l];
      float4 w41 = wo4[(4 * jg + 1) * 64 + l];
      float4 w42 = wo4[(4 * jg + 2) * 64 + l];
      float4 w43 = wo4[(4 * jg + 3) * 64 + l];
#pragma unroll
      for (int r = 0; r < 8; ++r) {
        float4 s4 = reinterpret_cast<const float4*>(bufA[w * 8 + r])[jg];
        fma4(acc[r], s4.x, w40);
        fma4(acc[r], s4.y, w41);
        fma4(acc[r], s4.z, w42);
        fma4(acc[r], s4.w, w43);
      }
    }
    float4 bo = reinterpret_cast<const float4*>(b_og)[l];
#pragma unroll
    for (int r = 0; r < 8; ++r) {
      float4 o;
      o.x = tanhf(acc[r].x + bo.x);
      o.y = tanhf(acc[r].y + bo.y);
      o.z = tanhf(acc[r].z + bo.z);
      o.w = tanhf(acc[r].w + bo.w);
      reinterpret_cast<float4*>(out)[(size_t)(row0 + r) * 64 + l] = o;
    }
  }
}

extern "C" void kernel_launch(void* const* d_in, const int* in_sizes, int n_in,
                              void* d_out, int out_size, void* d_ws,
                              size_t ws_size, hipStream_t stream) {
  const float* coords = (const float*)d_in[0];
  const float* ec_gamma = (const float*)d_in[1];
  const float* ec_beta = (const float*)d_in[2];
  const float* W_pp = (const float*)d_in[3];
  const float* b_pp = (const float*)d_in[4];
  const float* dg_gamma = (const float*)d_in[5];
  const float* dg_beta = (const float*)d_in[6];
  const float* W_mossy = (const float*)d_in[7];
  const float* W_rec = (const float*)d_in[8];
  const float* W_sc = (const float*)d_in[9];
  const float* b_sc = (const float*)d_in[10];
  const float* W_ta = (const float*)d_in[11];
  const float* b_ta = (const float*)d_in[12];
  const float* W_cs = (const float*)d_in[13];
  const float* W_cd = (const float*)d_in[14];
  const float* W_og = (const float*)d_in[15];
  const float* b_og = (const float*)d_in[16];
  float* out = (float*)d_out;

  float* ws = (float*)d_ws;
  float* colsum = ws;                       // 64
  float* WmT = colsum + 64;                 // 2048*256
  float* W_ppT = WmT + 2048 * 256;          // 64*2048
  float* W_recT = W_ppT + 64 * 2048;        // 256*256
  float* W_scT = W_recT + 256 * 256;
  float* W_csT = W_scT + 256 * 256;
  float* W_cdT = W_csT + 256 * 256;
  float* W_ogT = W_cdT + 256 * 256;
  float* W_taT = W_ogT + 256 * 256;         // 64*256
  float* cue_g = W_taT + 64 * 256;          // 32768*256

  hipMemsetAsync(colsum, 0, COORD * sizeof(float), stream);
  colsum_kernel<<<256, 256, 0, stream>>>(coords, colsum);
  transpose_any<<<(256 * 2048 + 255) / 256, 256, 0, stream>>>(W_mossy, WmT, 256, 2048);
  transpose_any<<<(2048 * 64 + 255) / 256, 256, 0, stream>>>(W_pp, W_ppT, 2048, 64);
  transpose_any<<<(256 * 256 + 255) / 256, 256, 0, stream>>>(W_rec, W_recT, 256, 256);
  transpose_any<<<(256 * 256 + 255) / 256, 256, 0, stream>>>(W_sc, W_scT, 256, 256);
  transpose_any<<<(256 * 256 + 255) / 256, 256, 0, stream>>>(W_cs, W_csT, 256, 256);
  transpose_any<<<(256 * 256 + 255) / 256, 256, 0, stream>>>(W_cd, W_cdT, 256, 256);
  transpose_any<<<(256 * 256 + 255) / 256, 256, 0, stream>>>(W_og, W_ogT, 256, 256);
  transpose_any<<<(256 * 64 + 255) / 256, 256, 0, stream>>>(W_ta, W_taT, 256, 64);

  mega1<<<B_N / 8, 512, 0, stream>>>(coords, colsum, ec_gamma, ec_beta, W_ppT,
                                     b_pp, dg_gamma, dg_beta, WmT, cue_g);
  mega2<<<B_N / 32, 256, 0, stream>>>(coords, colsum, ec_gamma, ec_beta, cue_g,
                                      W_recT, W_scT, b_sc, W_taT, b_ta, W_csT,
                                      W_cdT, W_ogT, b_og, out);
}